// Round 1
// baseline (1537.539 us; speedup 1.0000x reference)
//
#include <hip/hip_runtime.h>

#define NN   102400
#define EE   819200
#define GG   512
#define NPG  200
#define HID  64
#define DD   128
#define TT   64
#define BB   8
#define HH   4
#define DHH  32
#define LL   4

static __device__ __forceinline__ float wave_sum64(float v) {
#pragma unroll
    for (int off = 32; off > 0; off >>= 1) v += __shfl_xor(v, off, 64);
    return v;
}

static __device__ __forceinline__ float block_sum128(float v, float* sm) {
    v = wave_sum64(v);
    int wid = threadIdx.x >> 6;
    if ((threadIdx.x & 63) == 0) sm[wid] = v;
    __syncthreads();
    float r = sm[0] + sm[1];
    __syncthreads();
    return r;
}

// ---------------- GCN ----------------

__global__ void k_deg_init(float* __restrict__ deg) {
    int i = blockIdx.x * blockDim.x + threadIdx.x;
    if (i < NN) deg[i] = 1.0f;  // self loop
}

__global__ void k_deg_scatter(const int* __restrict__ dst, float* __restrict__ deg) {
    int e = blockIdx.x * blockDim.x + threadIdx.x;
    if (e < EE) atomicAdd(&deg[dst[e]], 1.0f);
}

__global__ void k_edge_w(const int* __restrict__ src, const int* __restrict__ dst,
                         const float* __restrict__ deg, float* __restrict__ ew) {
    int e = blockIdx.x * blockDim.x + threadIdx.x;
    if (e < EE) ew[e] = rsqrtf(deg[src[e]]) * rsqrtf(deg[dst[e]]);
}

__global__ void k_lin1(const float* __restrict__ x, const float* __restrict__ W,
                       float* __restrict__ out) {
    int idx = blockIdx.x * blockDim.x + threadIdx.x;  // NN*64
    int n = idx >> 6, j = idx & 63;
    if (n >= NN) return;
    out[idx] = x[2 * n] * W[j] + x[2 * n + 1] * W[64 + j];
}

template <int IN, int OUT>
__global__ void k_lin(const float* __restrict__ in, const float* __restrict__ W,
                      float* __restrict__ out) {
    int idx = blockIdx.x * blockDim.x + threadIdx.x;  // NN*OUT
    int n = idx / OUT, j = idx % OUT;
    if (n >= NN) return;
    const float* row = in + (long)n * IN;
    float acc = 0.f;
#pragma unroll 8
    for (int i = 0; i < IN; i++) acc += row[i] * W[i * OUT + j];
    out[idx] = acc;
}

template <int FW>
__global__ void k_agg_self(const float* __restrict__ t, const float* __restrict__ deg,
                           float* __restrict__ h) {
    int idx = blockIdx.x * blockDim.x + threadIdx.x;  // NN*FW
    int n = idx / FW;
    if (n >= NN) return;
    h[idx] = t[idx] / deg[n];  // dinv[n]^2 = 1/deg[n]
}

template <int FW>
__global__ void k_agg_edges(const int* __restrict__ src, const int* __restrict__ dst,
                            const float* __restrict__ ew, const float* __restrict__ t,
                            float* __restrict__ h) {
    long idx = (long)blockIdx.x * blockDim.x + threadIdx.x;  // EE*FW
    int e = (int)(idx / FW), j = (int)(idx % FW);
    if (e >= EE) return;
    atomicAdd(&h[(long)dst[e] * FW + j], t[(long)src[e] * FW + j] * ew[e]);
}

__global__ void k_post_ln64(float* __restrict__ h, const float* __restrict__ b,
                            const float* __restrict__ g, const float* __restrict__ bl) {
    int idx = blockIdx.x * blockDim.x + threadIdx.x;  // NN*64, wave per node
    int n = idx >> 6, j = idx & 63;
    if (n >= NN) return;
    float u = fmaxf(h[idx] + b[j], 0.f);
    float mean = wave_sum64(u) * (1.f / 64.f);
    float d = u - mean;
    float var = wave_sum64(d * d) * (1.f / 64.f);
    h[idx] = d * rsqrtf(var + 1e-5f) * g[j] + bl[j];
}

// readout: per-graph mean + gb3 + positional encoding
__global__ void k_readout(const float* __restrict__ h3, const float* __restrict__ b3,
                          float* __restrict__ seq) {
    int g = blockIdx.x, d = threadIdx.x;  // 512 blocks x 128
    const float* base = h3 + (long)g * NPG * DD;
    float s = 0.f;
    for (int i = 0; i < NPG; i++) s += base[i * DD + d];
    float val = s * (1.f / NPG) + b3[d];
    int t = g & (TT - 1);
    float freq = expf((float)(d & ~1) * (-9.210340371976184f / 128.f));
    float ang = (float)t * freq;
    val += (d & 1) ? cosf(ang) : sinf(ang);
    seq[g * DD + d] = val;
}

// ---------------- Transformer ----------------

__global__ void k_qkv(const float* __restrict__ seq, const float* __restrict__ W,
                      const float* __restrict__ b, float* __restrict__ qkv) {
    int m = blockIdx.x, t = threadIdx.x;  // 512 x 128
    __shared__ float row[DD];
    row[t] = seq[m * DD + t];
    __syncthreads();
    for (int o = t; o < 384; o += 128) {
        float acc = b[o];
        const float* wr = W + o * DD;
#pragma unroll 8
        for (int d = 0; d < DD; d++) acc += row[d] * wr[d];
        qkv[m * 384 + o] = acc;
    }
}

__global__ void k_attn(const float* __restrict__ qkv, float* __restrict__ abuf) {
    int b = blockIdx.x >> 2, h = blockIdx.x & 3;  // 32 blocks x 64
    __shared__ float K[TT][DHH], V[TT][DHH];
    int t = threadIdx.x;
    for (int idx = t; idx < TT * DHH; idx += 64) {
        int j = idx >> 5, d = idx & 31;
        K[j][d] = qkv[(b * TT + j) * 384 + 128 + h * DHH + d];
        V[j][d] = qkv[(b * TT + j) * 384 + 256 + h * DHH + d];
    }
    __syncthreads();
    float q[DHH];
    const float* qp = qkv + (b * TT + t) * 384 + h * DHH;
#pragma unroll
    for (int d = 0; d < DHH; d++) q[d] = qp[d];
    const float scale = 0.17677669529663687f;  // 1/sqrt(32)
    float sc[TT];
    float mx = -1e30f;
    for (int j = 0; j < TT; j++) {
        float a = 0.f;
#pragma unroll
        for (int d = 0; d < DHH; d++) a += q[d] * K[j][d];
        a *= scale;
        sc[j] = a;
        mx = fmaxf(mx, a);
    }
    float ssum = 0.f;
    for (int j = 0; j < TT; j++) { sc[j] = expf(sc[j] - mx); ssum += sc[j]; }
    float inv = 1.f / ssum;
    float* op = abuf + (b * TT + t) * DD + h * DHH;
    for (int d = 0; d < DHH; d++) {
        float a = 0.f;
        for (int j = 0; j < TT; j++) a += sc[j] * V[j][d];
        op[d] = a * inv;
    }
}

__global__ void k_proj_res_ln(float* __restrict__ seq, const float* __restrict__ abuf,
                              const float* __restrict__ Wo, const float* __restrict__ bo,
                              const float* __restrict__ g, const float* __restrict__ bl) {
    int m = blockIdx.x, d = threadIdx.x;  // 512 x 128
    __shared__ float row[DD];
    __shared__ float sm[2];
    row[d] = abuf[m * DD + d];
    __syncthreads();
    float acc = bo[d];
    const float* wr = Wo + d * DD;
#pragma unroll 8
    for (int k = 0; k < DD; k++) acc += row[k] * wr[k];
    float u = seq[m * DD + d] + acc;
    float mean = block_sum128(u, sm) * (1.f / 128.f);
    float dv = u - mean;
    float var = block_sum128(dv * dv, sm) * (1.f / 128.f);
    seq[m * DD + d] = dv * rsqrtf(var + 1e-5f) * g[d] + bl[d];
}

__global__ void k_ffn1(const float* __restrict__ seq, const float* __restrict__ W,
                       const float* __restrict__ b, float* __restrict__ f1) {
    int m = blockIdx.x, t = threadIdx.x;  // 512 x 128
    __shared__ float row[DD];
    row[t] = seq[m * DD + t];
    __syncthreads();
    for (int k = t; k < 512; k += 128) {
        float acc = b[k];
        const float* wr = W + k * DD;
#pragma unroll 8
        for (int d = 0; d < DD; d++) acc += row[d] * wr[d];
        f1[m * 512 + k] = fmaxf(acc, 0.f);
    }
}

__global__ void k_ffn2_res_ln(float* __restrict__ seq, const float* __restrict__ f1,
                              const float* __restrict__ W, const float* __restrict__ b,
                              const float* __restrict__ g, const float* __restrict__ bl) {
    int m = blockIdx.x, d = threadIdx.x;  // 512 x 128
    __shared__ float row[512];
    __shared__ float sm[2];
    for (int i = d; i < 512; i += 128) row[i] = f1[m * 512 + i];
    __syncthreads();
    float acc = b[d];
    const float* wr = W + d * 512;
#pragma unroll 8
    for (int k = 0; k < 512; k++) acc += row[k] * wr[k];
    float u = seq[m * DD + d] + acc;
    float mean = block_sum128(u, sm) * (1.f / 128.f);
    float dv = u - mean;
    float var = block_sum128(dv * dv, sm) * (1.f / 128.f);
    seq[m * DD + d] = dv * rsqrtf(var + 1e-5f) * g[d] + bl[d];
}

__global__ void k_head(const float* __restrict__ seq, const float* __restrict__ W1,
                       const float* __restrict__ b1, const float* __restrict__ W2,
                       const float* __restrict__ b2, float* __restrict__ out) {
    int b = blockIdx.x, t = threadIdx.x;  // 8 x 128
    __shared__ float pooled[DD];
    __shared__ float hid[64];
    float s = 0.f;
    for (int i = 0; i < TT; i++) s += seq[(b * TT + i) * DD + t];
    pooled[t] = s * (1.f / TT);
    __syncthreads();
    if (t < 64) {
        float a = b1[t];
        const float* wr = W1 + t * DD;
        for (int k = 0; k < DD; k++) a += pooled[k] * wr[k];
        hid[t] = fmaxf(a, 0.f);
    }
    __syncthreads();
    if (t < 2) {
        float a = b2[t];
        const float* wr = W2 + t * 64;
        for (int k = 0; k < 64; k++) a += hid[k] * wr[k];
        out[b * 2 + t] = a;
    }
}

// ---------------- host ----------------

extern "C" void kernel_launch(void* const* d_in, const int* in_sizes, int n_in,
                              void* d_out, int out_size, void* d_ws, size_t ws_size,
                              hipStream_t stream) {
    const float* x     = (const float*)d_in[0];
    const int*   esrc  = (const int*)d_in[1];
    const int*   edst  = (const int*)d_in[2];
    const float* gW1   = (const float*)d_in[4];
    const float* gb1   = (const float*)d_in[5];
    const float* ln1g  = (const float*)d_in[6];
    const float* ln1b  = (const float*)d_in[7];
    const float* gW2   = (const float*)d_in[8];
    const float* gb2   = (const float*)d_in[9];
    const float* ln2g  = (const float*)d_in[10];
    const float* ln2b  = (const float*)d_in[11];
    const float* gW3   = (const float*)d_in[12];
    const float* gb3   = (const float*)d_in[13];
    const float* tWqkv = (const float*)d_in[14];
    const float* tbqkv = (const float*)d_in[15];
    const float* tWo   = (const float*)d_in[16];
    const float* tbo   = (const float*)d_in[17];
    const float* tg1   = (const float*)d_in[18];
    const float* tb1   = (const float*)d_in[19];
    const float* tg2   = (const float*)d_in[20];
    const float* tb2   = (const float*)d_in[21];
    const float* tWf1  = (const float*)d_in[22];
    const float* tbf1  = (const float*)d_in[23];
    const float* tWf2  = (const float*)d_in[24];
    const float* tbf2  = (const float*)d_in[25];
    const float* hW1   = (const float*)d_in[26];
    const float* hb1   = (const float*)d_in[27];
    const float* hW2   = (const float*)d_in[28];
    const float* hb2   = (const float*)d_in[29];
    float* out = (float*)d_out;

    float* p = (float*)d_ws;
    float* deg  = p; p += NN;
    float* ew   = p; p += EE;
    float* bufA = p; p += (size_t)NN * DD;
    float* bufB = p; p += (size_t)NN * DD;
    float* seq  = p; p += GG * DD;
    float* qkv  = p; p += GG * 384;
    float* abuf = p; p += GG * DD;
    float* f1b  = p; p += GG * 512;

    const int BS = 256;
    // degrees + edge weights
    k_deg_init<<<(NN + BS - 1) / BS, BS, 0, stream>>>(deg);
    k_deg_scatter<<<(EE + BS - 1) / BS, BS, 0, stream>>>(edst, deg);
    k_edge_w<<<(EE + BS - 1) / BS, BS, 0, stream>>>(esrc, edst, deg, ew);

    // GCN layer 1: x(2) -> 64
    k_lin1<<<(NN * 64) / BS, BS, 0, stream>>>(x, gW1, bufA);
    k_agg_self<64><<<(NN * 64) / BS, BS, 0, stream>>>(bufA, deg, bufB);
    k_agg_edges<64><<<((long)EE * 64) / BS, BS, 0, stream>>>(esrc, edst, ew, bufA, bufB);
    k_post_ln64<<<(NN * 64) / BS, BS, 0, stream>>>(bufB, gb1, ln1g, ln1b);

    // GCN layer 2: 64 -> 64
    k_lin<64, 64><<<(NN * 64) / BS, BS, 0, stream>>>(bufB, gW2, bufA);
    k_agg_self<64><<<(NN * 64) / BS, BS, 0, stream>>>(bufA, deg, bufB);
    k_agg_edges<64><<<((long)EE * 64) / BS, BS, 0, stream>>>(esrc, edst, ew, bufA, bufB);
    k_post_ln64<<<(NN * 64) / BS, BS, 0, stream>>>(bufB, gb2, ln2g, ln2b);

    // GCN layer 3: 64 -> 128 (bias folded into readout)
    k_lin<64, 128><<<(NN * 128) / BS, BS, 0, stream>>>(bufB, gW3, bufA);
    k_agg_self<128><<<(NN * 128) / BS, BS, 0, stream>>>(bufA, deg, bufB);
    k_agg_edges<128><<<((long)EE * 128) / BS, BS, 0, stream>>>(esrc, edst, ew, bufA, bufB);

    // readout + PE
    k_readout<<<GG, DD, 0, stream>>>(bufB, gb3, seq);

    // transformer layers
    for (int l = 0; l < LL; l++) {
        k_qkv<<<GG, DD, 0, stream>>>(seq, tWqkv + (size_t)l * 384 * 128, tbqkv + l * 384, qkv);
        k_attn<<<BB * HH, TT, 0, stream>>>(qkv, abuf);
        k_proj_res_ln<<<GG, DD, 0, stream>>>(seq, abuf, tWo + (size_t)l * 128 * 128,
                                             tbo + l * 128, tg1 + l * 128, tb1 + l * 128);
        k_ffn1<<<GG, DD, 0, stream>>>(seq, tWf1 + (size_t)l * 512 * 128, tbf1 + l * 512, f1b);
        k_ffn2_res_ln<<<GG, DD, 0, stream>>>(seq, f1b, tWf2 + (size_t)l * 128 * 512,
                                             tbf2 + l * 128, tg2 + l * 128, tb2 + l * 128);
    }

    // head
    k_head<<<BB, DD, 0, stream>>>(seq, hW1, hb1, hW2, hb2, out);
}